// Round 6
// baseline (153.515 us; speedup 1.0000x reference)
//
#include <hip/hip_runtime.h>
#include <math.h>

// Problem shape (fixed by reference setup_inputs):
//   out:   (N=8, K=128, H=256, W=256) f32 logits
//   label: (N=8, 3, H, W) f32
//   centroids: (K=128, 3) f32
// Output: scalar f32 loss.
//
// Roofline: 268 MB logits + 25 MB label read exactly once -> ~46.5 us at the
// 6.3 TB/s achievable read BW. Single fused kernel: one pixel per thread,
// 2048 blocks = 8 waves/SIMD (max TLP), 16 nontemporal loads in flight per
// batch, last-block closer does the deterministic final reduction.

constexpr int K_CL   = 128;
constexpr int NIMG   = 8;
constexpr int HW     = 256 * 256;
constexpr int BLOCK  = 256;
constexpr int TOTAL_PIX = NIMG * HW;             // 524288
constexpr int NBLOCKS   = TOTAL_PIX / BLOCK;     // 2048 -> 8 waves/SIMD
constexpr float IGNORE_F = 255.0f;

__global__ __launch_bounds__(BLOCK) void cce_fused(
    const float* __restrict__ logits,
    const float* __restrict__ label,
    const float* __restrict__ cent,
    float* __restrict__ partial_num,
    float* __restrict__ partial_cnt,
    int*   __restrict__ counter,     // memset to 0 before launch
    float* __restrict__ out)
{
    // Stage centroids (x,y,z,|c|^2) in LDS; reads are wave-uniform broadcasts
    // (ds_read_b128 per k, same-address across lanes -> no conflicts).
    __shared__ float sc[K_CL][4];
    const int t = threadIdx.x;
    if (t < K_CL) {
        float x = cent[t * 3 + 0];
        float y = cent[t * 3 + 1];
        float z = cent[t * 3 + 2];
        sc[t][0] = x; sc[t][1] = y; sc[t][2] = z;
        sc[t][3] = x * x + y * y + z * z;
    }
    __syncthreads();

    const int P = blockIdx.x * BLOCK + t;        // global pixel id
    const int n = P >> 16;                       // P / HW
    const int p = P & (HW - 1);                  // P % HW

    // ---- label loads (3 channels, coalesced dword; read-once -> nt) ----
    const float* lb = label + ((long)n * 3) * HW + p;
    const float LX = __builtin_nontemporal_load(lb);
    const float LY = __builtin_nontemporal_load(lb + HW);
    const float LZ = __builtin_nontemporal_load(lb + 2 * HW);

    // ---- centroid argmin (matches reference d2 = |lab|^2 - 2*dot + |c|^2;
    //      strict < == first-occurrence argmin, same as jnp.argmin) ----
    const float slab = LX * LX + LY * LY + LZ * LZ;
    float best = INFINITY;
    int   idx  = 0;
#pragma unroll 8
    for (int k = 0; k < K_CL; ++k) {
        float dot = LX * sc[k][0] + LY * sc[k][1] + LZ * sc[k][2];
        float d   = slab - 2.0f * dot + sc[k][3];
        if (d < best) { best = d; idx = k; }
    }

    // ---- single pass over K logits: online softmax + capture picked logit.
    // m=-inf, s=0 makes k=0 uniform: e=exp(-inf)=0, up=true -> s=fma(0,0,1)=1.
    // Single-exp update (arg is always min(v,m)-max(v,m) = -|v-m|):
    //   v >  m : s = s*e + 1
    //   v <= m : s = s + e
    const float* ob = logits + ((long)n * K_CL) * HW + p;
    float m = -INFINITY, s = 0.0f, vsel = 0.0f;
#pragma unroll 2
    for (int kb = 0; kb < K_CL; kb += 16) {
        float w[16];
#pragma unroll
        for (int u = 0; u < 16; ++u)             // 16 independent nt loads in flight
            w[u] = __builtin_nontemporal_load(ob + (long)(kb + u) * HW);
#pragma unroll
        for (int u = 0; u < 16; ++u) {
            const int   k  = kb + u;
            const float vj = w[u];
            float e  = __expf(-fabsf(vj - m));
            bool  up = vj > m;
            s = up ? fmaf(s, e, 1.0f) : (s + e);
            m = fmaxf(m, vj);
            vsel = (k == idx) ? vj : vsel;
        }
    }

    // ---- per-pixel loss contribution (valid mask) ----
    const bool ignore = (LX == IGNORE_F) || (LY == IGNORE_F) || (LZ == IGNORE_F);
    float lsum = 0.0f, lcnt = 0.0f;
    if (!ignore) {
        lsum = vsel - m - __logf(s);
        lcnt = 1.0f;
    }

    // ---- wave (64-lane) shuffle reduce, then cross-wave via LDS ----
#pragma unroll
    for (int off = 32; off > 0; off >>= 1) {
        lsum += __shfl_down(lsum, off);
        lcnt += __shfl_down(lcnt, off);
    }
    __shared__ float wsum[BLOCK / 64], wcnt[BLOCK / 64];
    const int wave = t >> 6, lane = t & 63;
    if (lane == 0) { wsum[wave] = lsum; wcnt[wave] = lcnt; }
    __syncthreads();

    __shared__ int sdone;
    if (t == 0) {
        float a = 0.0f, c = 0.0f;
#pragma unroll
        for (int i = 0; i < BLOCK / 64; ++i) { a += wsum[i]; c += wcnt[i]; }
        partial_num[blockIdx.x] = a;
        partial_cnt[blockIdx.x] = c;
        // Release: orders the partial stores; agent scope crosses XCDs.
        int prev = __hip_atomic_fetch_add(counter, 1, __ATOMIC_ACQ_REL,
                                          __HIP_MEMORY_SCOPE_AGENT);
        sdone = (prev == NBLOCKS - 1);
    }
    __syncthreads();

    // ---- last block closes: deterministic fixed-order double reduction.
    // Output is bit-identical regardless of WHICH block closes.
    if (sdone) {
        double rs = 0.0, rc = 0.0;
        for (int i = t; i < NBLOCKS; i += BLOCK) {
            rs += (double)partial_num[i];
            rc += (double)partial_cnt[i];
        }
        __shared__ double sh_s[BLOCK], sh_c[BLOCK];
        sh_s[t] = rs; sh_c[t] = rc;
        __syncthreads();
        for (int off = BLOCK / 2; off > 0; off >>= 1) {
            if (t < off) { sh_s[t] += sh_s[t + off]; sh_c[t] += sh_c[t + off]; }
            __syncthreads();
        }
        if (t == 0) {
            double den = sh_c[0] > 1.0 ? sh_c[0] : 1.0;
            out[0] = (float)(-sh_s[0] / den);
        }
    }
}

extern "C" void kernel_launch(void* const* d_in, const int* in_sizes, int n_in,
                              void* d_out, int out_size, void* d_ws, size_t ws_size,
                              hipStream_t stream)
{
    const float* logits = (const float*)d_in[0];   // (N,K,H,W)
    const float* label  = (const float*)d_in[1];   // (N,3,H,W)
    const float* cent   = (const float*)d_in[2];   // (K,3)
    float* out = (float*)d_out;

    float* partial_num = (float*)d_ws;             // NBLOCKS floats
    float* partial_cnt = partial_num + NBLOCKS;    // NBLOCKS floats
    int*   counter     = (int*)(partial_cnt + NBLOCKS);

    // ws is poisoned (0xAA) before timing and never re-poisoned: the counter
    // must be zeroed every call. Memset node is graph-capturable.
    hipMemsetAsync(counter, 0, sizeof(int), stream);
    cce_fused<<<NBLOCKS, BLOCK, 0, stream>>>(logits, label, cent,
                                             partial_num, partial_cnt,
                                             counter, out);
}

// Round 7
// 131.338 us; speedup vs baseline: 1.1689x; 1.1689x over previous
//
#include <hip/hip_runtime.h>
#include <math.h>

// Problem shape (fixed by reference setup_inputs):
//   out:   (N=8, K=128, H=256, W=256) f32 logits
//   label: (N=8, 3, H, W) f32
//   centroids: (K=128, 3) f32
// Output: scalar f32 loss.
//
// Roofline: 268 MB logits + 25 MB label read exactly once -> ~46.5 us at
// 6.3 TB/s achievable read BW. One fused kernel: one pixel per thread,
// 2048 blocks = 8 waves/SIMD (max TLP), 8 plain (cached) loads per batch,
// last-block closer does the deterministic final reduction.
//
// Round-6 lesson: __builtin_nontemporal_load on the logits stream collapsed
// BW 3x (fetch undercounted + LLC residency forfeited). Plain loads only.

constexpr int K_CL   = 128;
constexpr int NIMG   = 8;
constexpr int HW     = 256 * 256;
constexpr int BLOCK  = 256;
constexpr int TOTAL_PIX = NIMG * HW;             // 524288
constexpr int NBLOCKS   = TOTAL_PIX / BLOCK;     // 2048 -> 8 waves/SIMD
constexpr float IGNORE_F = 255.0f;

__global__ __launch_bounds__(BLOCK) void cce_fused(
    const float* __restrict__ logits,
    const float* __restrict__ label,
    const float* __restrict__ cent,
    float* __restrict__ partial_num,
    float* __restrict__ partial_cnt,
    int*   __restrict__ counter,     // memset to 0 before launch
    float* __restrict__ out)
{
    // Stage centroids (x,y,z,|c|^2) in LDS; reads are wave-uniform broadcasts.
    __shared__ float sc[K_CL][4];
    const int t = threadIdx.x;
    if (t < K_CL) {
        float x = cent[t * 3 + 0];
        float y = cent[t * 3 + 1];
        float z = cent[t * 3 + 2];
        sc[t][0] = x; sc[t][1] = y; sc[t][2] = z;
        sc[t][3] = x * x + y * y + z * z;
    }
    __syncthreads();

    const int P = blockIdx.x * BLOCK + t;        // global pixel id
    const int n = P >> 16;                       // P / HW
    const int p = P & (HW - 1);                  // P % HW

    // ---- label loads (3 channels, coalesced dword: 256B/wave/channel) ----
    const float* lb = label + ((long)n * 3) * HW + p;
    const float LX = lb[0];
    const float LY = lb[HW];
    const float LZ = lb[2 * HW];

    // ---- centroid argmin (matches reference d2 = |lab|^2 - 2*dot + |c|^2;
    //      strict < == first-occurrence argmin, same as jnp.argmin) ----
    const float slab = LX * LX + LY * LY + LZ * LZ;
    float best = INFINITY;
    int   idx  = 0;
#pragma unroll 8
    for (int k = 0; k < K_CL; ++k) {
        float dot = LX * sc[k][0] + LY * sc[k][1] + LZ * sc[k][2];
        float d   = slab - 2.0f * dot + sc[k][3];
        if (d < best) { best = d; idx = k; }
    }

    // ---- single pass over K logits: online softmax + capture picked logit.
    // m=-inf, s=0 makes k=0 uniform: e=exp(-inf)=0, up=true -> s=fma(0,0,1)=1.
    // Single-exp update (arg is always min(v,m)-max(v,m) = -|v-m|):
    //   v >  m : s = s*e + 1
    //   v <= m : s = s + e
    const float* ob = logits + ((long)n * K_CL) * HW + p;
    float m = -INFINITY, s = 0.0f, vsel = 0.0f;
#pragma unroll 2
    for (int kb = 0; kb < K_CL; kb += 8) {
        float w[8];
#pragma unroll
        for (int u = 0; u < 8; ++u)                // 8 independent loads in flight
            w[u] = ob[(long)(kb + u) * HW];
#pragma unroll
        for (int u = 0; u < 8; ++u) {
            const int   k  = kb + u;
            const float vj = w[u];
            float e  = __expf(-fabsf(vj - m));
            bool  up = vj > m;
            s = up ? fmaf(s, e, 1.0f) : (s + e);
            m = fmaxf(m, vj);
            vsel = (k == idx) ? vj : vsel;
        }
    }

    // ---- per-pixel loss contribution (valid mask) ----
    const bool ignore = (LX == IGNORE_F) || (LY == IGNORE_F) || (LZ == IGNORE_F);
    float lsum = 0.0f, lcnt = 0.0f;
    if (!ignore) {
        lsum = vsel - m - __logf(s);
        lcnt = 1.0f;
    }

    // ---- wave (64-lane) shuffle reduce, then cross-wave via LDS ----
#pragma unroll
    for (int off = 32; off > 0; off >>= 1) {
        lsum += __shfl_down(lsum, off);
        lcnt += __shfl_down(lcnt, off);
    }
    __shared__ float wsum[BLOCK / 64], wcnt[BLOCK / 64];
    const int wave = t >> 6, lane = t & 63;
    if (lane == 0) { wsum[wave] = lsum; wcnt[wave] = lcnt; }
    __syncthreads();

    __shared__ int sdone;
    if (t == 0) {
        float a = 0.0f, c = 0.0f;
#pragma unroll
        for (int i = 0; i < BLOCK / 64; ++i) { a += wsum[i]; c += wcnt[i]; }
        partial_num[blockIdx.x] = a;
        partial_cnt[blockIdx.x] = c;
        // Release orders the partial stores; agent scope crosses XCDs.
        int prev = __hip_atomic_fetch_add(counter, 1, __ATOMIC_ACQ_REL,
                                          __HIP_MEMORY_SCOPE_AGENT);
        sdone = (prev == NBLOCKS - 1);
    }
    __syncthreads();

    // ---- last block closes: deterministic fixed-order double reduction.
    // Output is bit-identical regardless of WHICH block closes.
    if (sdone) {
        double rs = 0.0, rc = 0.0;
        for (int i = t; i < NBLOCKS; i += BLOCK) {
            rs += (double)partial_num[i];
            rc += (double)partial_cnt[i];
        }
        __shared__ double sh_s[BLOCK], sh_c[BLOCK];
        sh_s[t] = rs; sh_c[t] = rc;
        __syncthreads();
        for (int off = BLOCK / 2; off > 0; off >>= 1) {
            if (t < off) { sh_s[t] += sh_s[t + off]; sh_c[t] += sh_c[t + off]; }
            __syncthreads();
        }
        if (t == 0) {
            double den = sh_c[0] > 1.0 ? sh_c[0] : 1.0;
            out[0] = (float)(-sh_s[0] / den);
        }
    }
}

extern "C" void kernel_launch(void* const* d_in, const int* in_sizes, int n_in,
                              void* d_out, int out_size, void* d_ws, size_t ws_size,
                              hipStream_t stream)
{
    const float* logits = (const float*)d_in[0];   // (N,K,H,W)
    const float* label  = (const float*)d_in[1];   // (N,3,H,W)
    const float* cent   = (const float*)d_in[2];   // (K,3)
    float* out = (float*)d_out;

    float* partial_num = (float*)d_ws;             // NBLOCKS floats
    float* partial_cnt = partial_num + NBLOCKS;    // NBLOCKS floats
    int*   counter     = (int*)(partial_cnt + NBLOCKS);

    // ws is poisoned (0xAA) once before timing and never re-poisoned: the
    // counter must be zeroed every call. Memset node is graph-capturable.
    hipMemsetAsync(counter, 0, sizeof(int), stream);
    cce_fused<<<NBLOCKS, BLOCK, 0, stream>>>(logits, label, cent,
                                             partial_num, partial_cnt,
                                             counter, out);
}

// Round 8
// 53.926 us; speedup vs baseline: 2.8468x; 2.4355x over previous
//
#include <hip/hip_runtime.h>
#include <math.h>

// Problem shape (fixed by reference setup_inputs):
//   out:   (N=8, K=128, H=256, W=256) f32 logits
//   label: (N=8, 3, H, W) f32
//   centroids: (K=128, 3) f32
// Output: scalar f32 loss.
//
// Roofline: 268 MB logits + 25 MB label read exactly once -> ~46.5 us at the
// 6.3 TB/s achievable read BW. Two kernels: main (one pixel per thread,
// 2048 blocks = 8 waves/SIMD max TLP, 8 plain cached loads in flight per
// batch) + tiny deterministic reduce.
//
// Round-6/7 lessons (do NOT reintroduce):
//  - __builtin_nontemporal_load on the logits stream: BW collapse.
//  - Fused last-block closer with agent-scope ACQ_REL atomic per block:
//    2048 L2 writeback/invalidate pairs (XCD L2s non-coherent) -> 2.3-4x
//    slowdown. Cross-XCD sync belongs in a second kernel launch.

constexpr int K_CL   = 128;
constexpr int NIMG   = 8;
constexpr int HW     = 256 * 256;
constexpr int BLOCK  = 256;
constexpr int TOTAL_PIX = NIMG * HW;             // 524288
constexpr int NBLOCKS   = TOTAL_PIX / BLOCK;     // 2048 -> 8 waves/SIMD
constexpr float IGNORE_F = 255.0f;

__global__ __launch_bounds__(BLOCK) void cce_main(
    const float* __restrict__ logits,
    const float* __restrict__ label,
    const float* __restrict__ cent,
    float* __restrict__ partial_num,
    float* __restrict__ partial_cnt)
{
    // Stage centroids (x,y,z,|c|^2) in LDS; reads are wave-uniform broadcasts.
    __shared__ float sc[K_CL][4];
    const int t = threadIdx.x;
    if (t < K_CL) {
        float x = cent[t * 3 + 0];
        float y = cent[t * 3 + 1];
        float z = cent[t * 3 + 2];
        sc[t][0] = x; sc[t][1] = y; sc[t][2] = z;
        sc[t][3] = x * x + y * y + z * z;
    }
    __syncthreads();

    const int P = blockIdx.x * BLOCK + t;        // global pixel id
    const int n = P >> 16;                       // P / HW
    const int p = P & (HW - 1);                  // P % HW

    // ---- label loads (3 channels, coalesced dword: 256B/wave/channel) ----
    const float* lb = label + ((long)n * 3) * HW + p;
    const float LX = lb[0];
    const float LY = lb[HW];
    const float LZ = lb[2 * HW];

    // ---- centroid argmin (matches reference d2 = |lab|^2 - 2*dot + |c|^2;
    //      strict < == first-occurrence argmin, same as jnp.argmin) ----
    const float slab = LX * LX + LY * LY + LZ * LZ;
    float best = INFINITY;
    int   idx  = 0;
#pragma unroll 8
    for (int k = 0; k < K_CL; ++k) {
        float dot = LX * sc[k][0] + LY * sc[k][1] + LZ * sc[k][2];
        float d   = slab - 2.0f * dot + sc[k][3];
        if (d < best) { best = d; idx = k; }
    }

    // ---- single pass over K logits: online softmax + capture picked logit.
    // m=-inf, s=0 makes k=0 uniform: e=exp(-inf)=0, up=true -> s=fma(0,0,1)=1.
    // Single-exp update (arg is always min(v,m)-max(v,m) = -|v-m|):
    //   v >  m : s = s*e + 1
    //   v <= m : s = s + e
    const float* ob = logits + ((long)n * K_CL) * HW + p;
    float m = -INFINITY, s = 0.0f, vsel = 0.0f;
#pragma unroll 2
    for (int kb = 0; kb < K_CL; kb += 8) {
        float w[8];
#pragma unroll
        for (int u = 0; u < 8; ++u)                // 8 independent loads in flight
            w[u] = ob[(long)(kb + u) * HW];
#pragma unroll
        for (int u = 0; u < 8; ++u) {
            const int   k  = kb + u;
            const float vj = w[u];
            float e  = __expf(-fabsf(vj - m));
            bool  up = vj > m;
            s = up ? fmaf(s, e, 1.0f) : (s + e);
            m = fmaxf(m, vj);
            vsel = (k == idx) ? vj : vsel;
        }
    }

    // ---- per-pixel loss contribution (valid mask) ----
    const bool ignore = (LX == IGNORE_F) || (LY == IGNORE_F) || (LZ == IGNORE_F);
    float lsum = 0.0f, lcnt = 0.0f;
    if (!ignore) {
        lsum = vsel - m - __logf(s);
        lcnt = 1.0f;
    }

    // ---- wave (64-lane) shuffle reduce, then cross-wave via LDS ----
#pragma unroll
    for (int off = 32; off > 0; off >>= 1) {
        lsum += __shfl_down(lsum, off);
        lcnt += __shfl_down(lcnt, off);
    }
    __shared__ float wsum[BLOCK / 64], wcnt[BLOCK / 64];
    const int wave = t >> 6, lane = t & 63;
    if (lane == 0) { wsum[wave] = lsum; wcnt[wave] = lcnt; }
    __syncthreads();
    if (t == 0) {
        float a = 0.0f, c = 0.0f;
#pragma unroll
        for (int i = 0; i < BLOCK / 64; ++i) { a += wsum[i]; c += wcnt[i]; }
        partial_num[blockIdx.x] = a;
        partial_cnt[blockIdx.x] = c;
    }
}

// Deterministic final reduce: fixed-order strided sums in double, LDS tree.
__global__ __launch_bounds__(BLOCK) void cce_reduce(
    const float* __restrict__ partial_num,
    const float* __restrict__ partial_cnt,
    float* __restrict__ out,
    int nblocks)
{
    const int t = threadIdx.x;
    double s = 0.0, c = 0.0;
    for (int i = t; i < nblocks; i += BLOCK) {
        s += (double)partial_num[i];
        c += (double)partial_cnt[i];
    }
    __shared__ double sh_s[BLOCK], sh_c[BLOCK];
    sh_s[t] = s; sh_c[t] = c;
    __syncthreads();
    for (int off = BLOCK / 2; off > 0; off >>= 1) {
        if (t < off) { sh_s[t] += sh_s[t + off]; sh_c[t] += sh_c[t + off]; }
        __syncthreads();
    }
    if (t == 0) {
        double den = sh_c[0] > 1.0 ? sh_c[0] : 1.0;
        out[0] = (float)(-sh_s[0] / den);
    }
}

extern "C" void kernel_launch(void* const* d_in, const int* in_sizes, int n_in,
                              void* d_out, int out_size, void* d_ws, size_t ws_size,
                              hipStream_t stream)
{
    const float* logits = (const float*)d_in[0];   // (N,K,H,W)
    const float* label  = (const float*)d_in[1];   // (N,3,H,W)
    const float* cent   = (const float*)d_in[2];   // (K,3)
    float* out = (float*)d_out;

    float* partial_num = (float*)d_ws;             // NBLOCKS floats
    float* partial_cnt = partial_num + NBLOCKS;    // NBLOCKS floats

    cce_main<<<NBLOCKS, BLOCK, 0, stream>>>(logits, label, cent, partial_num, partial_cnt);
    cce_reduce<<<1, BLOCK, 0, stream>>>(partial_num, partial_cnt, out, NBLOCKS);
}

// Round 9
// 53.394 us; speedup vs baseline: 2.8751x; 1.0100x over previous
//
#include <hip/hip_runtime.h>
#include <math.h>

// Problem shape (fixed by reference setup_inputs):
//   out:   (N=8, K=128, H=256, W=256) f32 logits
//   label: (N=8, 3, H, W) f32
//   centroids: (K=128, 3) f32
// Output: scalar f32 loss.
//
// Roofline: 268 MB logits + 25 MB label read exactly once. Rounds 6/7 showed
// FETCH_SIZE ~134 MB (half the logits L3-resident across replays), so HBM is
// not saturated; the limit is latency/MLP. This round: software-pipelined
// double-buffered k-loop (8+8 loads in flight), first batch prefetched before
// the argmin loop.
//
// Do-NOT-reintroduce list (measured regressions):
//  - __builtin_nontemporal_load on the logits stream (round 6: BW collapse).
//  - Fused last-block closer w/ per-block agent-scope ACQ_REL atomic
//    (round 7: 2048 cross-XCD L2 writeback/invalidate pairs, 2.3-4x slower).

constexpr int K_CL   = 128;
constexpr int NIMG   = 8;
constexpr int HW     = 256 * 256;
constexpr int BLOCK  = 256;
constexpr int TOTAL_PIX = NIMG * HW;             // 524288
constexpr int NBLOCKS   = TOTAL_PIX / BLOCK;     // 2048 -> 8 waves/SIMD
constexpr float IGNORE_F = 255.0f;

__global__ __launch_bounds__(BLOCK) void cce_main(
    const float* __restrict__ logits,
    const float* __restrict__ label,
    const float* __restrict__ cent,
    float* __restrict__ partial_num,
    float* __restrict__ partial_cnt)
{
    // Stage centroids (x,y,z,|c|^2) in LDS; reads are wave-uniform broadcasts.
    __shared__ float sc[K_CL][4];
    const int t = threadIdx.x;
    if (t < K_CL) {
        float x = cent[t * 3 + 0];
        float y = cent[t * 3 + 1];
        float z = cent[t * 3 + 2];
        sc[t][0] = x; sc[t][1] = y; sc[t][2] = z;
        sc[t][3] = x * x + y * y + z * z;
    }
    __syncthreads();

    const int P = blockIdx.x * BLOCK + t;        // global pixel id
    const int n = P >> 16;                       // P / HW
    const int p = P & (HW - 1);                  // P % HW

    // ---- label loads (3 channels, coalesced dword: 256B/wave/channel) ----
    const float* lb = label + ((long)n * 3) * HW + p;
    const float LX = lb[0];
    const float LY = lb[HW];
    const float LZ = lb[2 * HW];

    const float* ob = logits + ((long)n * K_CL) * HW + p;

    // ---- prefetch first logits batch BEFORE the argmin loop so the first
    //      memory round-trip overlaps the LDS-resident argmin compute ----
    float w0[8], w1[8];
#pragma unroll
    for (int u = 0; u < 8; ++u)
        w0[u] = ob[(long)u * HW];

    // ---- centroid argmin (matches reference d2 = |lab|^2 - 2*dot + |c|^2;
    //      strict < == first-occurrence argmin, same as jnp.argmin) ----
    const float slab = LX * LX + LY * LY + LZ * LZ;
    float best = INFINITY;
    int   idx  = 0;
#pragma unroll 8
    for (int k = 0; k < K_CL; ++k) {
        float dot = LX * sc[k][0] + LY * sc[k][1] + LZ * sc[k][2];
        float d   = slab - 2.0f * dot + sc[k][3];
        if (d < best) { best = d; idx = k; }
    }

    // ---- single pass over K logits: online softmax + capture picked logit.
    // m=-inf, s=0 makes k=0 uniform: e=exp(-inf)=0, up=true -> s=fma(0,0,1)=1.
    // Single-exp update (arg is always min(v,m)-max(v,m) = -|v-m|):
    //   v >  m : s = s*e + 1
    //   v <= m : s = s + e
    // Software pipeline: consume w0 while w1's loads are in flight and vice
    // versa -> 8-16 loads outstanding continuously.
    float m = -INFINITY, s = 0.0f, vsel = 0.0f;
#pragma unroll
    for (int kb = 0; kb < K_CL; kb += 16) {
        // issue batch kb+8 .. kb+15
#pragma unroll
        for (int u = 0; u < 8; ++u)
            w1[u] = ob[(long)(kb + 8 + u) * HW];
        // consume batch kb .. kb+7
#pragma unroll
        for (int u = 0; u < 8; ++u) {
            const int   k  = kb + u;
            const float vj = w0[u];
            float e  = __expf(-fabsf(vj - m));
            bool  up = vj > m;
            s = up ? fmaf(s, e, 1.0f) : (s + e);
            m = fmaxf(m, vj);
            vsel = (k == idx) ? vj : vsel;
        }
        // issue batch kb+16 .. kb+23 (compile-time dead on last iteration)
        if (kb + 16 < K_CL) {
#pragma unroll
            for (int u = 0; u < 8; ++u)
                w0[u] = ob[(long)(kb + 16 + u) * HW];
        }
        // consume batch kb+8 .. kb+15
#pragma unroll
        for (int u = 0; u < 8; ++u) {
            const int   k  = kb + 8 + u;
            const float vj = w1[u];
            float e  = __expf(-fabsf(vj - m));
            bool  up = vj > m;
            s = up ? fmaf(s, e, 1.0f) : (s + e);
            m = fmaxf(m, vj);
            vsel = (k == idx) ? vj : vsel;
        }
    }

    // ---- per-pixel loss contribution (valid mask) ----
    const bool ignore = (LX == IGNORE_F) || (LY == IGNORE_F) || (LZ == IGNORE_F);
    float lsum = 0.0f, lcnt = 0.0f;
    if (!ignore) {
        lsum = vsel - m - __logf(s);
        lcnt = 1.0f;
    }

    // ---- wave (64-lane) shuffle reduce, then cross-wave via LDS ----
#pragma unroll
    for (int off = 32; off > 0; off >>= 1) {
        lsum += __shfl_down(lsum, off);
        lcnt += __shfl_down(lcnt, off);
    }
    __shared__ float wsum[BLOCK / 64], wcnt[BLOCK / 64];
    const int wave = t >> 6, lane = t & 63;
    if (lane == 0) { wsum[wave] = lsum; wcnt[wave] = lcnt; }
    __syncthreads();
    if (t == 0) {
        float a = 0.0f, c = 0.0f;
#pragma unroll
        for (int i = 0; i < BLOCK / 64; ++i) { a += wsum[i]; c += wcnt[i]; }
        partial_num[blockIdx.x] = a;
        partial_cnt[blockIdx.x] = c;
    }
}

// Deterministic final reduce: fixed-order strided sums in double, LDS tree.
__global__ __launch_bounds__(BLOCK) void cce_reduce(
    const float* __restrict__ partial_num,
    const float* __restrict__ partial_cnt,
    float* __restrict__ out,
    int nblocks)
{
    const int t = threadIdx.x;
    double s = 0.0, c = 0.0;
    for (int i = t; i < nblocks; i += BLOCK) {
        s += (double)partial_num[i];
        c += (double)partial_cnt[i];
    }
    __shared__ double sh_s[BLOCK], sh_c[BLOCK];
    sh_s[t] = s; sh_c[t] = c;
    __syncthreads();
    for (int off = BLOCK / 2; off > 0; off >>= 1) {
        if (t < off) { sh_s[t] += sh_s[t + off]; sh_c[t] += sh_c[t + off]; }
        __syncthreads();
    }
    if (t == 0) {
        double den = sh_c[0] > 1.0 ? sh_c[0] : 1.0;
        out[0] = (float)(-sh_s[0] / den);
    }
}

extern "C" void kernel_launch(void* const* d_in, const int* in_sizes, int n_in,
                              void* d_out, int out_size, void* d_ws, size_t ws_size,
                              hipStream_t stream)
{
    const float* logits = (const float*)d_in[0];   // (N,K,H,W)
    const float* label  = (const float*)d_in[1];   // (N,3,H,W)
    const float* cent   = (const float*)d_in[2];   // (K,3)
    float* out = (float*)d_out;

    float* partial_num = (float*)d_ws;             // NBLOCKS floats
    float* partial_cnt = partial_num + NBLOCKS;    // NBLOCKS floats

    cce_main<<<NBLOCKS, BLOCK, 0, stream>>>(logits, label, cent, partial_num, partial_cnt);
    cce_reduce<<<1, BLOCK, 0, stream>>>(partial_num, partial_cnt, out, NBLOCKS);
}